// Round 2
// 1304.428 us; speedup vs baseline: 1.0394x; 1.0394x over previous
//
#include <hip/hip_runtime.h>
#include <hip/hip_bf16.h>

#define F_IN 1433
#define F_HID 16
#define F_OUT 7
#define KSTEPS 45  // ceil(1433/32)

typedef __bf16 bf16x8 __attribute__((ext_vector_type(8)));
typedef float f32x4 __attribute__((ext_vector_type(4)));
typedef int i32x4 __attribute__((ext_vector_type(4)));
typedef unsigned short u16;
typedef unsigned int u32;

static __device__ __forceinline__ float bf2f(u16 b) {
    return __builtin_bit_cast(float, (u32)b << 16);
}
static __device__ __forceinline__ u16 f2bf(float f) {  // RNE fp32->bf16
    u32 u = __builtin_bit_cast(u32, f);
    u32 r = u + 0x7FFFu + ((u >> 16) & 1u);
    return (u16)(r >> 16);
}
static __device__ __forceinline__ int clampN(int v, int N) {
    return ((unsigned)v < (unsigned)N) ? v : 0;
}

// ---------------- init: zero deg + dtype detection ----------------
// flags[0]=1 if float tensors are bf16 (else fp32); flags[1]=1 if edge_index
// is int64 (else int32).
__global__ __launch_bounds__(256) void k_init(const u16* __restrict__ xu,
                                              const int* __restrict__ ei,
                                              int* __restrict__ flags,
                                              int* __restrict__ deg, int N) {
    int i = blockIdx.x * 256 + threadIdx.x;
    if (i < N) deg[i] = 0;
    if (blockIdx.x == 0 && threadIdx.x < 64) {
        int t = threadIdx.x;
        u16 v = xu[t];
        int e = (v >> 7) & 0xFF;
        unsigned long long mb = __ballot(e >= 100 && e <= 140);
        unsigned long long mz = __ballot(ei[2 * t + 1] == 0);
        if (t == 0) {
            flags[0] = (__popcll(mb) >= 56) ? 1 : 0;
            flags[1] = (__popcll(mz) >= 48) ? 1 : 0;
        }
    }
}

// edge accessors: value i of src row = ei[i<<sh], dst row = ei[(E+i)<<sh]
// (little-endian low word when int64).

// ---------------- CSR build ----------------

__global__ __launch_bounds__(256) void k_deg(const int* __restrict__ ei,
                                             const int* __restrict__ flags,
                                             int* __restrict__ deg, int E, int N) {
    int sh = flags[1];
    int i = blockIdx.x * 256 + threadIdx.x;
    if (i < E) {
        int d = ei[(size_t)(E + i) << sh];
        atomicAdd(&deg[clampN(d, N)], 1);
    }
}

__global__ __launch_bounds__(256) void k_scan1(const int* __restrict__ deg,
                                               int* __restrict__ rowoff,
                                               int* __restrict__ bsum, int N) {
    __shared__ int s[256];
    int t = threadIdx.x, i = blockIdx.x * 256 + t;
    int v = (i < N) ? deg[i] : 0;
    s[t] = v;
    __syncthreads();
    for (int o = 1; o < 256; o <<= 1) {
        int x = 0;
        if (t >= o) x = s[t - o];
        __syncthreads();
        s[t] += x;
        __syncthreads();
    }
    if (i < N) rowoff[i] = s[t] - v;
    if (t == 255) bsum[blockIdx.x] = s[255];
}

__global__ __launch_bounds__(1024) void k_scan2(const int* __restrict__ bsum,
                                                int* __restrict__ bscan, int NB) {
    __shared__ int s[1024];
    int t = threadIdx.x;
    int v = (t < NB) ? bsum[t] : 0;
    s[t] = v;
    __syncthreads();
    for (int o = 1; o < 1024; o <<= 1) {
        int x = 0;
        if (t >= o) x = s[t - o];
        __syncthreads();
        s[t] += x;
        __syncthreads();
    }
    if (t < NB) bscan[t] = s[t] - v;
}

__global__ __launch_bounds__(256) void k_scan3(const int* __restrict__ deg,
                                               int* __restrict__ rowoff,
                                               const int* __restrict__ bscan,
                                               int* __restrict__ fill,
                                               float* __restrict__ dis, int N) {
    int i = blockIdx.x * 256 + threadIdx.x;
    if (i >= N) return;
    int ro = rowoff[i] + bscan[blockIdx.x];
    rowoff[i] = ro;
    fill[i] = ro;
    dis[i] = rsqrtf((float)(deg[i] + 1));
}

__global__ __launch_bounds__(256) void k_fill(const int* __restrict__ ei,
                                              const int* __restrict__ flags,
                                              int* __restrict__ fill,
                                              int* __restrict__ csr, int E, int N) {
    int sh = flags[1];
    int i = blockIdx.x * 256 + threadIdx.x;
    if (i < E) {
        int d = ei[(size_t)(E + i) << sh];
        int s = ei[(size_t)i << sh];
        int slot = atomicAdd(&fill[clampN(d, N)], 1);
        if (slot >= 0 && slot < E) csr[slot] = clampN(s, N);
    }
}

// ---------------- GEMM1: hn = (x @ W1) * dis ----------------
// MFMA 16x16x32 bf16; A elems fetched per dtype (bf16 direct / fp32 RNE-cast).
// C/D: col=lane&15, row=quad*4+reg (m89-verified).

template <int ISBF>
static __device__ __forceinline__ void gemm_tiles(const u16* xu, const float* xf,
                                                  const u16* lw,
                                                  const float* __restrict__ dis,
                                                  float* __restrict__ hn, int N,
                                                  int tid, int bid, int grid) {
    int wave = tid >> 6, lane = tid & 63;
    int quad = lane >> 4, m = lane & 15;
    int ntiles = (N + 63) / 64;
    int k0 = quad * 8;

    for (int tb = bid; tb < ntiles; tb += grid) {
        int base = tb * 64 + wave * 16;
        int row = base + m;
        int rowc = row < N ? row : N - 1;
        const u16* xru = xu + (size_t)rowc * F_IN;
        const float* xrf = xf + (size_t)rowc * F_IN;

        f32x4 acc = {0.f, 0.f, 0.f, 0.f};
        for (int ks = 0; ks < KSTEPS - 1; ks++) {  // k < 1408 unguarded
            u16 e[8];
            if (ISBF) {
                const u16* xp = xru + k0 + ks * 32;
#pragma unroll
                for (int j = 0; j < 8; j++) e[j] = xp[j];
            } else {
                const float* xp = xrf + k0 + ks * 32;
#pragma unroll
                for (int j = 0; j < 8; j++) e[j] = f2bf(xp[j]);
            }
            i32x4 wv = {(int)((u32)e[0] | ((u32)e[1] << 16)),
                        (int)((u32)e[2] | ((u32)e[3] << 16)),
                        (int)((u32)e[4] | ((u32)e[5] << 16)),
                        (int)((u32)e[6] | ((u32)e[7] << 16))};
            bf16x8 a = __builtin_bit_cast(bf16x8, wv);
            bf16x8 b = __builtin_bit_cast(bf16x8, *(const i32x4*)(&lw[ks * 512 + lane * 8]));
            acc = __builtin_amdgcn_mfma_f32_16x16x32_bf16(a, b, acc, 0, 0, 0);
        }
        {  // tail: k in [1408,1440) guarded
            int ks = KSTEPS - 1;
            int kb = ks * 32 + k0;
            u16 e[8];
#pragma unroll
            for (int j = 0; j < 8; j++) {
                int k = kb + j;
                e[j] = (k < F_IN) ? (ISBF ? xru[k] : f2bf(xrf[k])) : (u16)0;
            }
            i32x4 wv = {(int)((u32)e[0] | ((u32)e[1] << 16)),
                        (int)((u32)e[2] | ((u32)e[3] << 16)),
                        (int)((u32)e[4] | ((u32)e[5] << 16)),
                        (int)((u32)e[6] | ((u32)e[7] << 16))};
            bf16x8 a = __builtin_bit_cast(bf16x8, wv);
            bf16x8 b = __builtin_bit_cast(bf16x8, *(const i32x4*)(&lw[ks * 512 + lane * 8]));
            acc = __builtin_amdgcn_mfma_f32_16x16x32_bf16(a, b, acc, 0, 0, 0);
        }
#pragma unroll
        for (int r = 0; r < 4; r++) {
            int orow = base + quad * 4 + r;
            if (orow < N) hn[(size_t)orow * 16 + m] = acc[r] * dis[orow];
        }
    }
}

__global__ __launch_bounds__(256) void k_gemm1(const void* __restrict__ x,
                                               const void* __restrict__ W1,
                                               const int* __restrict__ flags,
                                               const float* __restrict__ dis,
                                               float* __restrict__ hn, int N) {
    __shared__ __align__(16) u16 lw[KSTEPS * 512];
    int tid = threadIdx.x;
    int isbf = flags[0];
    const u16* W1u = (const u16*)W1;
    const float* W1f = (const float*)W1;
    for (int idx = tid; idx < KSTEPS * 512; idx += 256) {
        int j = idx & 7, lane = (idx >> 3) & 63, ks = idx >> 9;
        int quad = lane >> 4, n = lane & 15;
        int k = ks * 32 + quad * 8 + j;
        u16 w = 0;
        if (k < F_IN) w = isbf ? W1u[k * 16 + n] : f2bf(W1f[k * 16 + n]);
        lw[idx] = w;
    }
    __syncthreads();
    if (isbf)
        gemm_tiles<1>((const u16*)x, (const float*)x, lw, dis, hn, N, tid, blockIdx.x, gridDim.x);
    else
        gemm_tiles<0>((const u16*)x, (const float*)x, lw, dis, hn, N, tid, blockIdx.x, gridDim.x);
}

// ---------------- Aggregation layer 1 (pull over CSR) + fused linear 2 ----------------
// 16 lanes per node hold the 16 hidden cols. After relu, the 16x7 matvec for
// layer 2 is done in-wave via __shfl; writes tn[v*8 + 0..6] (*dis), col 7 = 0.

__global__ __launch_bounds__(256) void k_agg1(const float* __restrict__ hn,
                                              const int* __restrict__ csr,
                                              const int* __restrict__ rowoff,
                                              const int* __restrict__ deg,
                                              const float* __restrict__ dis,
                                              const void* __restrict__ b1,
                                              const void* __restrict__ W2,
                                              const int* __restrict__ flags,
                                              float* __restrict__ tn, int N) {
    int tid = threadIdx.x;
    int lane = tid & 63;
    int c = tid & 15, g = tid >> 4;
    int v = blockIdx.x * 16 + g;
    if (v >= N) return;
    int isbf = flags[0];
    float bc = isbf ? bf2f(((const u16*)b1)[c]) : ((const float*)b1)[c];

    float acc = hn[(size_t)v * 16 + c];  // self-loop
    int s0 = rowoff[v], d = deg[v];
    const int* cp = csr + s0;
    float a1 = 0.f, a2 = 0.f, a3 = 0.f;
    int i = 0;
    for (; i + 4 <= d; i += 4) {  // 4 independent accumulators -> 4 gathers in flight
        int sA = cp[i], sB = cp[i + 1], sC = cp[i + 2], sD = cp[i + 3];
        acc += hn[(size_t)sA * 16 + c];
        a1 += hn[(size_t)sB * 16 + c];
        a2 += hn[(size_t)sC * 16 + c];
        a3 += hn[(size_t)sD * 16 + c];
    }
    for (; i < d; i++) acc += hn[(size_t)cp[i] * 16 + c];
    acc += (a1 + a2) + a3;

    float dv = dis[v];
    float y = fmaxf(acc * dv + bc, 0.f);  // y1[v][c]

    // fused layer-2 linear: lane c<7 computes tn[v][c] = (sum_k y_k W2[k][c]) * dv
    float w2c[16];
#pragma unroll
    for (int k = 0; k < 16; k++) {
        float w = 0.f;
        if (c < 7) w = isbf ? bf2f(((const u16*)W2)[k * 7 + c]) : ((const float*)W2)[k * 7 + c];
        w2c[k] = w;
    }
    float s = 0.f;
#pragma unroll
    for (int k = 0; k < 16; k++) {
        float yk = __shfl(y, (lane & 48) + k, 64);  // y of lane k within this 16-lane group
        s += yk * w2c[k];
    }
    if (c < 8) tn[(size_t)v * 8 + c] = (c < 7) ? s * dv : 0.f;
}

// ---------------- Aggregation layer 2 + log_softmax ----------------

__global__ __launch_bounds__(256) void k_agg2(const float* __restrict__ tn,
                                              const int* __restrict__ csr,
                                              const int* __restrict__ rowoff,
                                              const int* __restrict__ deg,
                                              const float* __restrict__ dis,
                                              const void* __restrict__ b2,
                                              const int* __restrict__ flags,
                                              void* __restrict__ out, int N) {
    int tid = threadIdx.x;
    int c = tid & 7, g = tid >> 3;
    int v = blockIdx.x * 32 + g;
    if (v >= N) return;
    int isbf = flags[0];
    float bc = 0.f;
    if (c < 7) bc = isbf ? bf2f(((const u16*)b2)[c]) : ((const float*)b2)[c];

    float acc = tn[(size_t)v * 8 + c];  // self-loop; col 7 = 0 pad
    int s0 = rowoff[v], d = deg[v];
    const int* cp = csr + s0;
    float a1 = 0.f, a2 = 0.f, a3 = 0.f;
    int i = 0;
    for (; i + 4 <= d; i += 4) {
        int sA = cp[i], sB = cp[i + 1], sC = cp[i + 2], sD = cp[i + 3];
        acc += tn[(size_t)sA * 8 + c];
        a1 += tn[(size_t)sB * 8 + c];
        a2 += tn[(size_t)sC * 8 + c];
        a3 += tn[(size_t)sD * 8 + c];
    }
    for (; i < d; i++) acc += tn[(size_t)cp[i] * 8 + c];
    acc += (a1 + a2) + a3;

    float z = (c < 7) ? (acc * dis[v] + bc) : -1e30f;
    float mx = z;
#pragma unroll
    for (int o = 1; o < 8; o <<= 1) mx = fmaxf(mx, __shfl_xor(mx, o, 8));
    float ex = (c < 7) ? expf(z - mx) : 0.f;
    float sm = ex;
#pragma unroll
    for (int o = 1; o < 8; o <<= 1) sm += __shfl_xor(sm, o, 8);
    sm = fmaxf(sm, 1e-30f);
    if (c < 7) {
        float res = z - mx - logf(sm);
        if (isbf)
            ((u16*)out)[(size_t)v * 7 + c] = f2bf(res);
        else
            ((float*)out)[(size_t)v * 7 + c] = res;
    }
}

// ---------------- launch ----------------

extern "C" void kernel_launch(void* const* d_in, const int* in_sizes, int n_in,
                              void* d_out, int out_size, void* d_ws, size_t ws_size,
                              hipStream_t stream) {
    const void* x = d_in[0];
    const int* ei = (const int*)d_in[1];
    const void* W1 = d_in[2];
    const void* b1 = d_in[3];
    const void* W2 = d_in[4];
    const void* b2 = d_in[5];

    int N = in_sizes[0] / F_IN;
    int E = in_sizes[1] / 2;

    char* p = (char*)d_ws;
    size_t off = 0;
    auto alloc = [&](size_t bytes) -> void* {
        off = (off + 255) & ~(size_t)255;
        void* r = p + off;
        off += bytes;
        return r;
    };
    int* flags = (int*)alloc(256);
    int* deg = (int*)alloc((size_t)N * 4);
    int* rowoff = (int*)alloc((size_t)N * 4);
    int* fill = (int*)alloc((size_t)N * 4);
    int* bsum = (int*)alloc(1024 * 4);
    int* bscan = (int*)alloc(1024 * 4);
    float* dis = (float*)alloc((size_t)N * 4);
    int* csr = (int*)alloc((size_t)E * 4);
    float* hn = (float*)alloc((size_t)N * 16 * 4);
    float* tn = (float*)alloc((size_t)N * 8 * 4);
    (void)ws_size;
    (void)n_in;
    (void)out_size;

    int gE = (E + 255) / 256;
    int gN = (N + 255) / 256;

    k_init<<<gN, 256, 0, stream>>>((const u16*)x, ei, flags, deg, N);
    k_deg<<<gE, 256, 0, stream>>>(ei, flags, deg, E, N);
    k_scan1<<<gN, 256, 0, stream>>>(deg, rowoff, bsum, N);
    k_scan2<<<1, 1024, 0, stream>>>(bsum, bscan, gN);
    k_scan3<<<gN, 256, 0, stream>>>(deg, rowoff, bscan, fill, dis, N);
    k_fill<<<gE, 256, 0, stream>>>(ei, flags, fill, csr, E, N);

    int ntiles = (N + 63) / 64;
    int gg = ntiles < 768 ? ntiles : 768;
    k_gemm1<<<gg, 256, 0, stream>>>(x, W1, flags, dis, hn, N);

    k_agg1<<<(N + 15) / 16, 256, 0, stream>>>(hn, csr, rowoff, deg, dis, b1, W2, flags, tn, N);
    k_agg2<<<(N + 31) / 32, 256, 0, stream>>>(tn, csr, rowoff, deg, dis, b2, flags, d_out, N);
}